// Round 11
// baseline (113.233 us; speedup 1.0000x reference)
//
#include <hip/hip_runtime.h>

#define HALO 3
#define SUB_H 64        /* rows per wave */
#define WAVES_Y 2       /* waves per block (independent y-subtiles) */
#define STRIP_OUT 240   /* output columns per wave; input strip = 256 cols */
#define EPS 0.002f
#define RING 10         /* register ring of raw rows (7 window + 3 prefetch) */

#define NSTRIPS 13
#define NYT 16          /* y-tiles (of WAVES_Y*SUB_H=128 rows) */
#define NCH 3
#define NWG (NSTRIPS * NYT * NCH)   /* 624 */
#define NXCD 8
#define QXCD (NWG / NXCD)           /* 78, NWG%8==0 -> bijective */

typedef float f32x4 __attribute__((ext_vector_type(4)));

__device__ __forceinline__ float rcp_fast(float x) { return __builtin_amdgcn_rcpf(x); }

// Whole-wave lane shifts at VALU speed (no LDS pipe, no lgkm waits).
// 0x138 = wf_sr1: lane i <- lane i-1 (lane 0 <- 0 via bound_ctrl)  == shfl_up(1)
// 0x130 = wf_sl1: lane i <- lane i+1 (lane 63 <- 0)                == shfl_down(1)
__device__ __forceinline__ float dpp_up1(float x) {
    return __int_as_float(__builtin_amdgcn_update_dpp(0, __float_as_int(x), 0x138, 0xf, 0xf, true));
}
__device__ __forceinline__ float dpp_dn1(float x) {
    return __int_as_float(__builtin_amdgcn_update_dpp(0, __float_as_int(x), 0x130, 0xf, 0xf, true));
}

// 2 independent waves per block, each owning a 64-row x 240-col output tile.
// Raw input rows in a 10-deep register ring (fully unrolled -> compile-time
// indices); add-rows prefetched 3 iterations ahead; horizontal 7-sums via DPP
// wave shifts. No LDS, no barriers. NT stores.
// XCD swizzle: work is assigned column-major so vertically-adjacent tiles
// (which share 6 halo rows) co-reside on one XCD's L2.
__global__ __launch_bounds__(64 * WAVES_Y) void ProgressiveTransfer_kernel(
    const float* __restrict__ G, const float* __restrict__ S,
    float* __restrict__ out, int H, int W)
{
    const int t  = threadIdx.x;                        // lane 0..63
    const int wv = threadIdx.y;

    // ---- bijective XCD swizzle (m204; NWG % 8 == 0 so q-form suffices) ----
    const int orig = blockIdx.x + NSTRIPS * (blockIdx.y + NYT * blockIdx.z);
    const int wg   = (orig % NXCD) * QXCD + orig / NXCD;
    // column-major decode: consecutive wg walk DOWN a strip column
    const int ch  = wg / (NSTRIPS * NYT);
    const int rem = wg - ch * (NSTRIPS * NYT);
    const int sx  = rem / NYT;                         // strip index 0..12
    const int sy  = rem % NYT;                         // y-tile index 0..15

    const int y0 = (sy * WAVES_Y + wv) * SUB_H;
    const int col0 = sx * STRIP_OUT - 8 + 4 * t;
    const bool cin = (col0 >= 0) && (col0 + 3 < W);    // float4 all-in or all-out

    const size_t plane = (size_t)H * W;
    const float* Gp = G + (size_t)ch * plane;
    const float* Sp = S + (size_t)ch * plane;

    auto ld = [&](const float* __restrict__ P, int r) -> f32x4 {
        if (cin && r >= 0 && r < H)
            return *reinterpret_cast<const f32x4*>(P + (size_t)r * W + col0);
        return (f32x4){0.f, 0.f, 0.f, 0.f};
    };

    // Ring slot for image row r is (r - y0 + 3) mod RING.
    f32x4 rg[RING], rs[RING];

    // Vertical window sums over rows [y-3, y+3] for the lane's 4 columns.
    float g1[4] = {0,0,0,0}, g2[4] = {0,0,0,0};
    float s1[4] = {0,0,0,0}, s2[4] = {0,0,0,0};

    // Prologue: rows y0-3..y0+2 -> slots 0..5 (init), y0+3..y0+5 -> slots 6..8
    // (prefetch for iters 0..2). 18 loads issued back-to-back (max MLP).
#pragma unroll
    for (int k = 0; k < 9; ++k) rg[k] = ld(Gp, y0 - HALO + k);
#pragma unroll
    for (int k = 0; k < 9; ++k) rs[k] = ld(Sp, y0 - HALO + k);
#pragma unroll
    for (int k = 0; k < 6; ++k) {
#pragma unroll
        for (int j = 0; j < 4; ++j) {
            g1[j] += rg[k][j]; g2[j] = fmaf(rg[k][j], rg[k][j], g2[j]);
            s1[j] += rs[k][j]; s2[j] = fmaf(rs[k][j], rs[k][j], s2[j]);
        }
    }

    // Per-column horizontal clipped counts (loop-invariant).
    float cntx[4];
#pragma unroll
    for (int j = 0; j < 4; ++j) {
        const int x = col0 + j;
        cntx[j] = (float)(min(x + HALO, W - 1) - max(x - HALO, 0) + 1);
    }

    const bool wout = (t >= 2) && (t < 62) && (col0 < W);

#pragma unroll
    for (int i = 0; i < SUB_H; ++i) {
        const int y = y0 + i;

        // Drop row y-4 from the ring (slot holds zeros when y-4 < 0).
        if (i >= 1) {
            const int sl = (i - 1) % RING;
#pragma unroll
            for (int j = 0; j < 4; ++j) {
                g1[j] -= rg[sl][j]; g2[j] = fmaf(-rg[sl][j], rg[sl][j], g2[j]);
                s1[j] -= rs[sl][j]; s2[j] = fmaf(-rs[sl][j], rs[sl][j], s2[j]);
            }
        }
        // Gain row y+3 (loaded 3 iterations ago).
        {
            const int al = (i + 6) % RING;
#pragma unroll
            for (int j = 0; j < 4; ++j) {
                g1[j] += rg[al][j]; g2[j] = fmaf(rg[al][j], rg[al][j], g2[j]);
                s1[j] += rs[al][j]; s2[j] = fmaf(rs[al][j], rs[al][j], s2[j]);
            }
        }
        // Prefetch add-row of iteration i+3 (row y+6) into its slot.
        // (Slot (i+9)%RING was sub-read above in this same iteration.)
        if (i + 3 < SUB_H) {
            const int pl = (i + 9) % RING;
            rg[pl] = ld(Gp, y + 6);
            rs[pl] = ld(Sp, y + 6);
        }

        // Horizontal 7-sums via DPP wave shifts (pure VALU).
        float hg1[4], hg2[4], hs1[4], hs2[4];
        auto hsum = [&](const float* c, float* o) {
            const float t1 = c[0] + c[1], t2 = c[2] + c[3];
            const float S4 = t1 + t2;
            const float sfx3 = c[1] + t2;     // c1+c2+c3
            const float pfx3 = t1 + c[2];     // c0+c1+c2
            const float S1m = dpp_up1(c[3]);
            const float S2m = dpp_up1(t2);
            const float S3m = dpp_up1(sfx3);
            const float P1p = dpp_dn1(c[0]);
            const float P2p = dpp_dn1(t1);
            const float P3p = dpp_dn1(pfx3);
            o[0] = S3m + S4;
            o[1] = S2m + S4 + P1p;
            o[2] = S1m + S4 + P2p;
            o[3] = S4 + P3p;
        };
        hsum(g1, hg1); hsum(g2, hg2); hsum(s1, hs1); hsum(s2, hs2);

        const float cnty = (float)(min(y + HALO, H - 1) - max(y - HALO, 0) + 1);

        f32x4 av, bv;
#pragma unroll
        for (int j = 0; j < 4; ++j) {
            const float cnt  = cntx[j] * cnty;
            const float inv  = rcp_fast(cnt);
            const float invm = rcp_fast(cnt - 1.0f);
            const float mg = hg1[j] * inv;
            const float ms = hs1[j] * inv;
            const float varg = (hg2[j] - hg1[j] * mg) * invm;
            const float vars = (hs2[j] - hs1[j] * ms) * invm;
            const float stdg = __builtin_amdgcn_sqrtf(fmaxf(varg, 0.0f));
            const float stds = __builtin_amdgcn_sqrtf(fmaxf(vars, 0.0f));
            const float alpha = stdg * rcp_fast(stds + EPS);
            av[j] = alpha;
            bv[j] = mg - alpha * ms;
        }

        if (wout) {
            const size_t base = (size_t)ch * plane + (size_t)y * W + col0;
            __builtin_nontemporal_store(av, reinterpret_cast<f32x4*>(out + base));
            __builtin_nontemporal_store(bv, reinterpret_cast<f32x4*>(out + 3 * plane + base));
        }
    }
}

extern "C" void kernel_launch(void* const* d_in, const int* in_sizes, int n_in,
                              void* d_out, int out_size, void* d_ws, size_t ws_size,
                              hipStream_t stream) {
    (void)n_in; (void)d_ws; (void)ws_size; (void)in_sizes; (void)out_size;
    const float* guidance = (const float*)d_in[0];
    const float* source   = (const float*)d_in[1];
    float* out = (float*)d_out;

    const int H = 2048, W = 3072;

    dim3 block(64, WAVES_Y, 1);
    dim3 grid(NSTRIPS, NYT, NCH);                      // 13 x 16 x 3 = 624
    ProgressiveTransfer_kernel<<<grid, block, 0, stream>>>(guidance, source, out, H, W);
}

// Round 12
// 64.896 us; speedup vs baseline: 1.7449x; 1.7449x over previous
//
#include <hip/hip_runtime.h>

#define HALO 3
#define SUB_H 64        /* rows per wave */
#define WAVES_Y 2       /* waves per block (independent y-subtiles) */
#define STRIP_OUT 240   /* output columns per wave; input strip = 256 cols */
#define EPS 0.002f
#define RING 16         /* ring slots; CHUNK==RING so slot = gi%16 = I (literal) */
#define CHUNK 16

#define NSTRIPS 13
#define NYT 16          /* y-tiles (of WAVES_Y*SUB_H=128 rows) */
#define NCH 3
#define NWG (NSTRIPS * NYT * NCH)   /* 624 */
#define NXCD 8
#define QXCD (NWG / NXCD)           /* 78, NWG%8==0 -> bijective */

typedef float f32x4 __attribute__((ext_vector_type(4)));

__device__ __forceinline__ float rcp_fast(float x) { return __builtin_amdgcn_rcpf(x); }

// Whole-wave lane shifts at VALU speed.
// 0x138 = wf_sr1: lane i <- lane i-1 (lane 0 <- 0)   == shfl_up(1)
// 0x130 = wf_sl1: lane i <- lane i+1 (lane 63 <- 0)  == shfl_down(1)
__device__ __forceinline__ float dpp_up1(float x) {
    return __int_as_float(__builtin_amdgcn_update_dpp(0, __float_as_int(x), 0x138, 0xf, 0xf, true));
}
__device__ __forceinline__ float dpp_dn1(float x) {
    return __int_as_float(__builtin_amdgcn_update_dpp(0, __float_as_int(x), 0x130, 0xf, 0xf, true));
}

// Ring slot for image row r is (r - y0 + 3) mod 16. Iteration gi (y=y0+gi):
//   sub slot (gi-1)%16, add slot (gi+6)%16, prefetch(row y+6) slot (gi+9)%16.
// CHUNK==RING makes slots depend only on I = gi%16, so a 16-step macro body
// with literal I keeps ALL ring indices compile-time even inside a runtime
// chunk loop -> ring stays in VGPRs (round-11 lesson: spill detector is
// WRITE_SIZE; must stay ~148 MB).
#define RSTEP(I, DO_SUB, DO_PF)                                               \
  {                                                                           \
    const int y = ybase + (I);                                                \
    enum { SL = ((I) + RING - 1) % RING,                                      \
           AL = ((I) + 6) % RING,                                             \
           PL = ((I) + 9) % RING };                                           \
    if (DO_SUB) {                                                             \
      _Pragma("unroll") for (int j = 0; j < 4; ++j) {                         \
        g1[j] -= rg[SL][j]; g2[j] = fmaf(-rg[SL][j], rg[SL][j], g2[j]);       \
        s1[j] -= rs[SL][j]; s2[j] = fmaf(-rs[SL][j], rs[SL][j], s2[j]);       \
      }                                                                       \
    }                                                                         \
    _Pragma("unroll") for (int j = 0; j < 4; ++j) {                           \
      g1[j] += rg[AL][j]; g2[j] = fmaf(rg[AL][j], rg[AL][j], g2[j]);          \
      s1[j] += rs[AL][j]; s2[j] = fmaf(rs[AL][j], rs[AL][j], s2[j]);          \
    }                                                                         \
    if (DO_PF) { rg[PL] = ld(Gp, y + 6); rs[PL] = ld(Sp, y + 6); }            \
    emit_row(y);                                                              \
  }

__global__ __launch_bounds__(64 * WAVES_Y) void ProgressiveTransfer_kernel(
    const float* __restrict__ G, const float* __restrict__ S,
    float* __restrict__ out, int H, int W)
{
    const int t  = threadIdx.x;                        // lane 0..63
    const int wv = threadIdx.y;

    // ---- bijective XCD swizzle, column-major decode (vertical L2 locality) --
    const int orig = blockIdx.x + NSTRIPS * (blockIdx.y + NYT * blockIdx.z);
    const int wg   = (orig % NXCD) * QXCD + orig / NXCD;
    const int ch  = wg / (NSTRIPS * NYT);
    const int rem = wg - ch * (NSTRIPS * NYT);
    const int sx  = rem / NYT;                         // strip index 0..12
    const int sy  = rem % NYT;                         // y-tile index 0..15

    const int y0 = (sy * WAVES_Y + wv) * SUB_H;
    const int col0 = sx * STRIP_OUT - 8 + 4 * t;
    const bool cin = (col0 >= 0) && (col0 + 3 < W);    // float4 all-in or all-out

    const size_t plane = (size_t)H * W;
    const float* Gp = G + (size_t)ch * plane;
    const float* Sp = S + (size_t)ch * plane;

    auto ld = [&](const float* __restrict__ P, int r) -> f32x4 {
        if (cin && r >= 0 && r < H)
            return *reinterpret_cast<const f32x4*>(P + (size_t)r * W + col0);
        return (f32x4){0.f, 0.f, 0.f, 0.f};
    };

    f32x4 rg[RING], rs[RING];

    // Vertical window sums over rows [y-3, y+3] for the lane's 4 columns.
    float g1[4] = {0,0,0,0}, g2[4] = {0,0,0,0};
    float s1[4] = {0,0,0,0}, s2[4] = {0,0,0,0};

    // Prologue: rows y0-3..y0+2 -> slots 0..5 (init), y0+3..y0+5 -> slots 6..8
    // (prefetch for iters 0..2). 18 loads issued back-to-back.
#pragma unroll
    for (int k = 0; k < 9; ++k) rg[k] = ld(Gp, y0 - HALO + k);
#pragma unroll
    for (int k = 0; k < 9; ++k) rs[k] = ld(Sp, y0 - HALO + k);
#pragma unroll
    for (int k = 0; k < 6; ++k) {
#pragma unroll
        for (int j = 0; j < 4; ++j) {
            g1[j] += rg[k][j]; g2[j] = fmaf(rg[k][j], rg[k][j], g2[j]);
            s1[j] += rs[k][j]; s2[j] = fmaf(rs[k][j], rs[k][j], s2[j]);
        }
    }
    // Remaining ring slots (9..15) are written by prefetch before first read.

    // Per-column horizontal clipped counts (loop-invariant).
    float cntx[4];
#pragma unroll
    for (int j = 0; j < 4; ++j) {
        const int x = col0 + j;
        cntx[j] = (float)(min(x + HALO, W - 1) - max(x - HALO, 0) + 1);
    }

    const bool wout = (t >= 2) && (t < 62) && (col0 < W);

    // Per-row epilogue: horizontal 7-sums via DPP + stats + NT store.
    auto emit_row = [&](int y) {
        float hg1[4], hg2[4], hs1[4], hs2[4];
        auto hsum = [&](const float* c, float* o) {
            const float t1 = c[0] + c[1], t2 = c[2] + c[3];
            const float S4 = t1 + t2;
            const float sfx3 = c[1] + t2;     // c1+c2+c3
            const float pfx3 = t1 + c[2];     // c0+c1+c2
            const float S1m = dpp_up1(c[3]);
            const float S2m = dpp_up1(t2);
            const float S3m = dpp_up1(sfx3);
            const float P1p = dpp_dn1(c[0]);
            const float P2p = dpp_dn1(t1);
            const float P3p = dpp_dn1(pfx3);
            o[0] = S3m + S4;
            o[1] = S2m + S4 + P1p;
            o[2] = S1m + S4 + P2p;
            o[3] = S4 + P3p;
        };
        hsum(g1, hg1); hsum(g2, hg2); hsum(s1, hs1); hsum(s2, hs2);

        const float cnty = (float)(min(y + HALO, H - 1) - max(y - HALO, 0) + 1);

        f32x4 av, bv;
#pragma unroll
        for (int j = 0; j < 4; ++j) {
            const float cnt  = cntx[j] * cnty;
            const float inv  = rcp_fast(cnt);
            const float invm = rcp_fast(cnt - 1.0f);
            const float mg = hg1[j] * inv;
            const float ms = hs1[j] * inv;
            const float varg = (hg2[j] - hg1[j] * mg) * invm;
            const float vars = (hs2[j] - hs1[j] * ms) * invm;
            const float stdg = __builtin_amdgcn_sqrtf(fmaxf(varg, 0.0f));
            const float stds = __builtin_amdgcn_sqrtf(fmaxf(vars, 0.0f));
            const float alpha = stdg * rcp_fast(stds + EPS);
            av[j] = alpha;
            bv[j] = mg - alpha * ms;
        }

        if (wout) {
            const size_t base = (size_t)ch * plane + (size_t)y * W + col0;
            __builtin_nontemporal_store(av, reinterpret_cast<f32x4*>(out + base));
            __builtin_nontemporal_store(bv, reinterpret_cast<f32x4*>(out + 3 * plane + base));
        }
    };

    // ---- chunk 0 (gi = 0..15): peel the no-sub first step ----
    {
        const int ybase = y0;
        RSTEP(0,  false, true) RSTEP(1,  true, true) RSTEP(2,  true, true)
        RSTEP(3,  true,  true) RSTEP(4,  true, true) RSTEP(5,  true, true)
        RSTEP(6,  true,  true) RSTEP(7,  true, true) RSTEP(8,  true, true)
        RSTEP(9,  true,  true) RSTEP(10, true, true) RSTEP(11, true, true)
        RSTEP(12, true,  true) RSTEP(13, true, true) RSTEP(14, true, true)
        RSTEP(15, true,  true)
    }
    // ---- chunks 1..2 (runtime loop; slots identical since CHUNK==RING) ----
    for (int c = 1; c <= 2; ++c) {
        const int ybase = y0 + c * CHUNK;
        RSTEP(0,  true, true) RSTEP(1,  true, true) RSTEP(2,  true, true)
        RSTEP(3,  true, true) RSTEP(4,  true, true) RSTEP(5,  true, true)
        RSTEP(6,  true, true) RSTEP(7,  true, true) RSTEP(8,  true, true)
        RSTEP(9,  true, true) RSTEP(10, true, true) RSTEP(11, true, true)
        RSTEP(12, true, true) RSTEP(13, true, true) RSTEP(14, true, true)
        RSTEP(15, true, true)
    }
    // ---- chunk 3 (gi = 48..63): last 3 steps skip prefetch (gi+3 >= 64) ----
    {
        const int ybase = y0 + 3 * CHUNK;
        RSTEP(0,  true, true)  RSTEP(1,  true, true)  RSTEP(2,  true, true)
        RSTEP(3,  true, true)  RSTEP(4,  true, true)  RSTEP(5,  true, true)
        RSTEP(6,  true, true)  RSTEP(7,  true, true)  RSTEP(8,  true, true)
        RSTEP(9,  true, true)  RSTEP(10, true, true)  RSTEP(11, true, true)
        RSTEP(12, true, true)  RSTEP(13, true, false) RSTEP(14, true, false)
        RSTEP(15, true, false)
    }
}

extern "C" void kernel_launch(void* const* d_in, const int* in_sizes, int n_in,
                              void* d_out, int out_size, void* d_ws, size_t ws_size,
                              hipStream_t stream) {
    (void)n_in; (void)d_ws; (void)ws_size; (void)in_sizes; (void)out_size;
    const float* guidance = (const float*)d_in[0];
    const float* source   = (const float*)d_in[1];
    float* out = (float*)d_out;

    const int H = 2048, W = 3072;

    dim3 block(64, WAVES_Y, 1);
    dim3 grid(NSTRIPS, NYT, NCH);                      // 13 x 16 x 3 = 624
    ProgressiveTransfer_kernel<<<grid, block, 0, stream>>>(guidance, source, out, H, W);
}

// Round 13
// 62.037 us; speedup vs baseline: 1.8252x; 1.0461x over previous
//
#include <hip/hip_runtime.h>

#define HALO 3
#define SUB_H 64        /* rows per wave */
#define WAVES_Y 2       /* waves per block (independent y-subtiles) */
#define STRIP_OUT 120   /* output cols per wave; input strip = 128 cols (2/lane) */
#define EPS 0.002f
#define RING 16         /* ring slots; CHUNK==RING so slot = gi%16 = I (literal) */
#define CHUNK 16

#define NSTRIPS 26
#define NYT 16          /* y-tiles (of WAVES_Y*SUB_H=128 rows) */
#define NCH 3
#define NWG (NSTRIPS * NYT * NCH)   /* 1248 */
#define NXCD 8
#define QXCD (NWG / NXCD)           /* 156, NWG%8==0 -> bijective */

typedef float f32x2 __attribute__((ext_vector_type(2)));

__device__ __forceinline__ float rcp_fast(float x) { return __builtin_amdgcn_rcpf(x); }

// Whole-wave lane shifts at VALU speed.
// 0x138 = wf_sr1: lane i <- lane i-1 (lane 0 <- 0)   == shfl_up(1)
// 0x130 = wf_sl1: lane i <- lane i+1 (lane 63 <- 0)  == shfl_down(1)
__device__ __forceinline__ float dpp_up1(float x) {
    return __int_as_float(__builtin_amdgcn_update_dpp(0, __float_as_int(x), 0x138, 0xf, 0xf, true));
}
__device__ __forceinline__ float dpp_dn1(float x) {
    return __int_as_float(__builtin_amdgcn_update_dpp(0, __float_as_int(x), 0x130, 0xf, 0xf, true));
}

// Ring slot for image row r is (r - y0 + 3) mod 16. Iteration gi (y=y0+gi):
//   sub slot (gi-1)%16, add slot (gi+6)%16, prefetch(row y+6) slot (gi+9)%16.
// CHUNK==RING: slots depend only on I = gi%16 -> literal indices inside a
// runtime chunk loop -> ring stays in VGPRs (spill detector: WRITE_SIZE).
#define RSTEP(I, DO_SUB, DO_PF)                                               \
  {                                                                           \
    const int y = ybase + (I);                                                \
    enum { SL = ((I) + RING - 1) % RING,                                      \
           AL = ((I) + 6) % RING,                                             \
           PL = ((I) + 9) % RING };                                           \
    if (DO_SUB) {                                                             \
      _Pragma("unroll") for (int j = 0; j < 2; ++j) {                         \
        g1[j] -= rg[SL][j]; g2[j] = fmaf(-rg[SL][j], rg[SL][j], g2[j]);       \
        s1[j] -= rs[SL][j]; s2[j] = fmaf(-rs[SL][j], rs[SL][j], s2[j]);       \
      }                                                                       \
    }                                                                         \
    _Pragma("unroll") for (int j = 0; j < 2; ++j) {                           \
      g1[j] += rg[AL][j]; g2[j] = fmaf(rg[AL][j], rg[AL][j], g2[j]);          \
      s1[j] += rs[AL][j]; s2[j] = fmaf(rs[AL][j], rs[AL][j], s2[j]);          \
    }                                                                         \
    if (DO_PF) { rg[PL] = ld(Gp, y + 6); rs[PL] = ld(Sp, y + 6); }            \
    emit_row(y);                                                              \
  }

__global__ __launch_bounds__(64 * WAVES_Y) void ProgressiveTransfer_kernel(
    const float* __restrict__ G, const float* __restrict__ S,
    float* __restrict__ out, int H, int W)
{
    const int t  = threadIdx.x;                        // lane 0..63
    const int wv = threadIdx.y;

    // ---- bijective XCD swizzle, column-major decode (vertical L2 locality) --
    const int orig = blockIdx.x + NSTRIPS * (blockIdx.y + NYT * blockIdx.z);
    const int wg   = (orig % NXCD) * QXCD + orig / NXCD;
    const int ch  = wg / (NSTRIPS * NYT);
    const int rem = wg - ch * (NSTRIPS * NYT);
    const int sx  = rem / NYT;                         // strip index 0..25
    const int sy  = rem % NYT;                         // y-tile index 0..15

    const int y0 = (sy * WAVES_Y + wv) * SUB_H;
    const int col0 = sx * STRIP_OUT - 4 + 2 * t;       // lane's first column
    const bool cin = (col0 >= 0) && (col0 < W);        // float2 all-in or all-out (even)

    const size_t plane = (size_t)H * W;
    const float* Gp = G + (size_t)ch * plane;
    const float* Sp = S + (size_t)ch * plane;

    auto ld = [&](const float* __restrict__ P, int r) -> f32x2 {
        if (cin && r >= 0 && r < H)
            return *reinterpret_cast<const f32x2*>(P + (size_t)r * W + col0);
        return (f32x2){0.f, 0.f};
    };

    f32x2 rg[RING], rs[RING];

    // Vertical window sums over rows [y-3, y+3] for the lane's 2 columns.
    float g1[2] = {0,0}, g2[2] = {0,0};
    float s1[2] = {0,0}, s2[2] = {0,0};

    // Prologue: rows y0-3..y0+2 -> slots 0..5 (init), y0+3..y0+5 -> slots 6..8
    // (prefetch for iters 0..2). 18 loads issued back-to-back.
#pragma unroll
    for (int k = 0; k < 9; ++k) rg[k] = ld(Gp, y0 - HALO + k);
#pragma unroll
    for (int k = 0; k < 9; ++k) rs[k] = ld(Sp, y0 - HALO + k);
#pragma unroll
    for (int k = 0; k < 6; ++k) {
#pragma unroll
        for (int j = 0; j < 2; ++j) {
            g1[j] += rg[k][j]; g2[j] = fmaf(rg[k][j], rg[k][j], g2[j]);
            s1[j] += rs[k][j]; s2[j] = fmaf(rs[k][j], rs[k][j], s2[j]);
        }
    }
    // Ring slots 9..15 are written by prefetch before first read.

    // Per-column horizontal clipped counts (loop-invariant).
    float cntx[2];
#pragma unroll
    for (int j = 0; j < 2; ++j) {
        const int x = col0 + j;
        cntx[j] = (float)(min(x + HALO, W - 1) - max(x - HALO, 0) + 1);
    }

    const bool wout = (t >= 2) && (t < 62) && (col0 < W);

    // Per-row epilogue: horizontal 7-sums via DPP + stats + NT store.
    // 2 cols/lane: window [c0-3,c0+3] = up2(c1) + up1(P) + P + dn1(P);
    //              window [c1-3,c1+3] = up1(P) + P + dn1(P) + dn2(c0).
    auto emit_row = [&](int y) {
        float hg1[2], hg2[2], hs1[2], hs2[2];
        auto hsum = [&](const float* c, float* o) {
            const float P  = c[0] + c[1];
            const float Pu = dpp_up1(P);
            const float Pd = dpp_dn1(P);
            const float M  = Pu + P + Pd;
            const float u2 = dpp_up1(dpp_up1(c[1]));
            const float d2 = dpp_dn1(dpp_dn1(c[0]));
            o[0] = M + u2;
            o[1] = M + d2;
        };
        hsum(g1, hg1); hsum(g2, hg2); hsum(s1, hs1); hsum(s2, hs2);

        const float cnty = (float)(min(y + HALO, H - 1) - max(y - HALO, 0) + 1);

        f32x2 av, bv;
#pragma unroll
        for (int j = 0; j < 2; ++j) {
            const float cnt  = cntx[j] * cnty;
            const float inv  = rcp_fast(cnt);
            const float invm = rcp_fast(cnt - 1.0f);
            const float mg = hg1[j] * inv;
            const float ms = hs1[j] * inv;
            const float varg = (hg2[j] - hg1[j] * mg) * invm;
            const float vars = (hs2[j] - hs1[j] * ms) * invm;
            const float stdg = __builtin_amdgcn_sqrtf(fmaxf(varg, 0.0f));
            const float stds = __builtin_amdgcn_sqrtf(fmaxf(vars, 0.0f));
            const float alpha = stdg * rcp_fast(stds + EPS);
            av[j] = alpha;
            bv[j] = mg - alpha * ms;
        }

        if (wout) {
            const size_t base = (size_t)ch * plane + (size_t)y * W + col0;
            __builtin_nontemporal_store(av, reinterpret_cast<f32x2*>(out + base));
            __builtin_nontemporal_store(bv, reinterpret_cast<f32x2*>(out + 3 * plane + base));
        }
    };

    // ---- chunk 0 (gi = 0..15): peel the no-sub first step ----
    {
        const int ybase = y0;
        RSTEP(0,  false, true) RSTEP(1,  true, true) RSTEP(2,  true, true)
        RSTEP(3,  true,  true) RSTEP(4,  true, true) RSTEP(5,  true, true)
        RSTEP(6,  true,  true) RSTEP(7,  true, true) RSTEP(8,  true, true)
        RSTEP(9,  true,  true) RSTEP(10, true, true) RSTEP(11, true, true)
        RSTEP(12, true,  true) RSTEP(13, true, true) RSTEP(14, true, true)
        RSTEP(15, true,  true)
    }
    // ---- chunks 1..2 (runtime loop; slots identical since CHUNK==RING) ----
    for (int c = 1; c <= 2; ++c) {
        const int ybase = y0 + c * CHUNK;
        RSTEP(0,  true, true) RSTEP(1,  true, true) RSTEP(2,  true, true)
        RSTEP(3,  true, true) RSTEP(4,  true, true) RSTEP(5,  true, true)
        RSTEP(6,  true, true) RSTEP(7,  true, true) RSTEP(8,  true, true)
        RSTEP(9,  true, true) RSTEP(10, true, true) RSTEP(11, true, true)
        RSTEP(12, true, true) RSTEP(13, true, true) RSTEP(14, true, true)
        RSTEP(15, true, true)
    }
    // ---- chunk 3 (gi = 48..63): last 3 steps skip prefetch ----
    {
        const int ybase = y0 + 3 * CHUNK;
        RSTEP(0,  true, true)  RSTEP(1,  true, true)  RSTEP(2,  true, true)
        RSTEP(3,  true, true)  RSTEP(4,  true, true)  RSTEP(5,  true, true)
        RSTEP(6,  true, true)  RSTEP(7,  true, true)  RSTEP(8,  true, true)
        RSTEP(9,  true, true)  RSTEP(10, true, true)  RSTEP(11, true, true)
        RSTEP(12, true, true)  RSTEP(13, true, false) RSTEP(14, true, false)
        RSTEP(15, true, false)
    }
}

extern "C" void kernel_launch(void* const* d_in, const int* in_sizes, int n_in,
                              void* d_out, int out_size, void* d_ws, size_t ws_size,
                              hipStream_t stream) {
    (void)n_in; (void)d_ws; (void)ws_size; (void)in_sizes; (void)out_size;
    const float* guidance = (const float*)d_in[0];
    const float* source   = (const float*)d_in[1];
    float* out = (float*)d_out;

    const int H = 2048, W = 3072;

    dim3 block(64, WAVES_Y, 1);
    dim3 grid(NSTRIPS, NYT, NCH);                      // 26 x 16 x 3 = 1248
    ProgressiveTransfer_kernel<<<grid, block, 0, stream>>>(guidance, source, out, H, W);
}

// Round 14
// 59.476 us; speedup vs baseline: 1.9038x; 1.0431x over previous
//
#include <hip/hip_runtime.h>

#define HALO 3
#define SUB_H 32        /* rows per wave */
#define WAVES_Y 2       /* waves per block (independent y-subtiles) */
#define STRIP_OUT 248   /* output cols per wave; input strip = 256 cols */
#define EPS 0.002f
#define RING 10         /* register ring of raw rows (7 window + 3 prefetch) */

#define NSTRIPS 13      /* 13*248 = 3224 >= 3072 */
#define NYT 32          /* y-tiles (of WAVES_Y*SUB_H=64 rows) */
#define NCH 3
#define NWG (NSTRIPS * NYT * NCH)   /* 1248 */
#define NXCD 8
#define QXCD (NWG / NXCD)           /* 156, NWG%8==0 -> bijective */

typedef float f32x4 __attribute__((ext_vector_type(4)));

__device__ __forceinline__ float rcp_fast(float x) { return __builtin_amdgcn_rcpf(x); }

// Whole-wave lane shifts at VALU speed (no LDS pipe, no lgkm waits).
// 0x138 = wf_sr1: lane i <- lane i-1 (lane 0 <- 0 via bound_ctrl)  == shfl_up(1)
// 0x130 = wf_sl1: lane i <- lane i+1 (lane 63 <- 0)                == shfl_down(1)
__device__ __forceinline__ float dpp_up1(float x) {
    return __int_as_float(__builtin_amdgcn_update_dpp(0, __float_as_int(x), 0x138, 0xf, 0xf, true));
}
__device__ __forceinline__ float dpp_dn1(float x) {
    return __int_as_float(__builtin_amdgcn_update_dpp(0, __float_as_int(x), 0x130, 0xf, 0xf, true));
}

// 2 independent waves per block, each owning a 32-row x 248-col output tile.
// Raw input rows in a 10-deep register ring (fully unrolled -> compile-time
// indices); add-rows prefetched 3 iterations ahead; horizontal 7-sums via DPP
// wave shifts (window spans only +-1 lane, so lanes 1..62 all emit output).
// No LDS, no barriers. NT stores. Column-major XCD swizzle for vertical L2
// locality (round 9: -8 MB fetch, -4.4 us).
__global__ __launch_bounds__(64 * WAVES_Y) void ProgressiveTransfer_kernel(
    const float* __restrict__ G, const float* __restrict__ S,
    float* __restrict__ out, int H, int W)
{
    const int t  = threadIdx.x;                        // lane 0..63
    const int wv = threadIdx.y;

    // ---- bijective XCD swizzle (m204; NWG % 8 == 0 so q-form suffices) ----
    const int orig = blockIdx.x + NSTRIPS * (blockIdx.y + NYT * blockIdx.z);
    const int wg   = (orig % NXCD) * QXCD + orig / NXCD;
    // column-major decode: consecutive wg walk DOWN a strip column
    const int ch  = wg / (NSTRIPS * NYT);
    const int rem = wg - ch * (NSTRIPS * NYT);
    const int sx  = rem / NYT;                         // strip index 0..12
    const int sy  = rem % NYT;                         // y-tile index 0..31

    const int y0 = (sy * WAVES_Y + wv) * SUB_H;
    const int col0 = sx * STRIP_OUT - 4 + 4 * t;       // lane's first column
    const bool cin = (col0 >= 0) && (col0 + 3 < W);    // float4 all-in or all-out

    const size_t plane = (size_t)H * W;
    const float* Gp = G + (size_t)ch * plane;
    const float* Sp = S + (size_t)ch * plane;

    auto ld = [&](const float* __restrict__ P, int r) -> f32x4 {
        if (cin && r >= 0 && r < H)
            return *reinterpret_cast<const f32x4*>(P + (size_t)r * W + col0);
        return (f32x4){0.f, 0.f, 0.f, 0.f};
    };

    // Ring slot for image row r is (r - y0 + 3) mod RING.
    f32x4 rg[RING], rs[RING];

    // Vertical window sums over rows [y-3, y+3] for the lane's 4 columns.
    float g1[4] = {0,0,0,0}, g2[4] = {0,0,0,0};
    float s1[4] = {0,0,0,0}, s2[4] = {0,0,0,0};

    // Prologue: rows y0-3..y0+2 -> slots 0..5 (init), y0+3..y0+5 -> slots 6..8
    // (prefetch for iters 0..2). 18 loads issued back-to-back (max MLP).
#pragma unroll
    for (int k = 0; k < 9; ++k) rg[k] = ld(Gp, y0 - HALO + k);
#pragma unroll
    for (int k = 0; k < 9; ++k) rs[k] = ld(Sp, y0 - HALO + k);
#pragma unroll
    for (int k = 0; k < 6; ++k) {
#pragma unroll
        for (int j = 0; j < 4; ++j) {
            g1[j] += rg[k][j]; g2[j] = fmaf(rg[k][j], rg[k][j], g2[j]);
            s1[j] += rs[k][j]; s2[j] = fmaf(rs[k][j], rs[k][j], s2[j]);
        }
    }

    // Per-column horizontal clipped counts (loop-invariant).
    float cntx[4];
#pragma unroll
    for (int j = 0; j < 4; ++j) {
        const int x = col0 + j;
        cntx[j] = (float)(min(x + HALO, W - 1) - max(x - HALO, 0) + 1);
    }

    const bool wout = (t >= 1) && (t < 63) && (col0 < W);

#pragma unroll
    for (int i = 0; i < SUB_H; ++i) {
        const int y = y0 + i;

        // Drop row y-4 from the ring (slot holds zeros when y-4 < 0).
        if (i >= 1) {
            const int sl = (i - 1) % RING;
#pragma unroll
            for (int j = 0; j < 4; ++j) {
                g1[j] -= rg[sl][j]; g2[j] = fmaf(-rg[sl][j], rg[sl][j], g2[j]);
                s1[j] -= rs[sl][j]; s2[j] = fmaf(-rs[sl][j], rs[sl][j], s2[j]);
            }
        }
        // Gain row y+3 (loaded 3 iterations ago).
        {
            const int al = (i + 6) % RING;
#pragma unroll
            for (int j = 0; j < 4; ++j) {
                g1[j] += rg[al][j]; g2[j] = fmaf(rg[al][j], rg[al][j], g2[j]);
                s1[j] += rs[al][j]; s2[j] = fmaf(rs[al][j], rs[al][j], s2[j]);
            }
        }
        // Prefetch add-row of iteration i+3 (row y+6) into its slot.
        // (Slot (i+9)%RING was sub-read above in this same iteration.)
        if (i + 3 < SUB_H) {
            const int pl = (i + 9) % RING;
            rg[pl] = ld(Gp, y + 6);
            rs[pl] = ld(Sp, y + 6);
        }

        // Horizontal 7-sums via DPP wave shifts (pure VALU).
        float hg1[4], hg2[4], hs1[4], hs2[4];
        auto hsum = [&](const float* c, float* o) {
            const float t1 = c[0] + c[1], t2 = c[2] + c[3];
            const float S4 = t1 + t2;
            const float sfx3 = c[1] + t2;     // c1+c2+c3
            const float pfx3 = t1 + c[2];     // c0+c1+c2
            const float S1m = dpp_up1(c[3]);
            const float S2m = dpp_up1(t2);
            const float S3m = dpp_up1(sfx3);
            const float P1p = dpp_dn1(c[0]);
            const float P2p = dpp_dn1(t1);
            const float P3p = dpp_dn1(pfx3);
            o[0] = S3m + S4;
            o[1] = S2m + S4 + P1p;
            o[2] = S1m + S4 + P2p;
            o[3] = S4 + P3p;
        };
        hsum(g1, hg1); hsum(g2, hg2); hsum(s1, hs1); hsum(s2, hs2);

        const float cnty = (float)(min(y + HALO, H - 1) - max(y - HALO, 0) + 1);

        f32x4 av, bv;
#pragma unroll
        for (int j = 0; j < 4; ++j) {
            const float cnt  = cntx[j] * cnty;
            const float inv  = rcp_fast(cnt);
            const float invm = rcp_fast(cnt - 1.0f);
            const float mg = hg1[j] * inv;
            const float ms = hs1[j] * inv;
            const float varg = (hg2[j] - hg1[j] * mg) * invm;
            const float vars = (hs2[j] - hs1[j] * ms) * invm;
            const float stdg = __builtin_amdgcn_sqrtf(fmaxf(varg, 0.0f));
            const float stds = __builtin_amdgcn_sqrtf(fmaxf(vars, 0.0f));
            const float alpha = stdg * rcp_fast(stds + EPS);
            av[j] = alpha;
            bv[j] = mg - alpha * ms;
        }

        if (wout) {
            const size_t base = (size_t)ch * plane + (size_t)y * W + col0;
            __builtin_nontemporal_store(av, reinterpret_cast<f32x4*>(out + base));
            __builtin_nontemporal_store(bv, reinterpret_cast<f32x4*>(out + 3 * plane + base));
        }
    }
}

extern "C" void kernel_launch(void* const* d_in, const int* in_sizes, int n_in,
                              void* d_out, int out_size, void* d_ws, size_t ws_size,
                              hipStream_t stream) {
    (void)n_in; (void)d_ws; (void)ws_size; (void)in_sizes; (void)out_size;
    const float* guidance = (const float*)d_in[0];
    const float* source   = (const float*)d_in[1];
    float* out = (float*)d_out;

    const int H = 2048, W = 3072;

    dim3 block(64, WAVES_Y, 1);
    dim3 grid(NSTRIPS, NYT, NCH);                      // 13 x 32 x 3 = 1248
    ProgressiveTransfer_kernel<<<grid, block, 0, stream>>>(guidance, source, out, H, W);
}

// Round 15
// 58.767 us; speedup vs baseline: 1.9268x; 1.0121x over previous
//
#include <hip/hip_runtime.h>

#define HALO 3
#define SUB_H 32        /* rows per wave */
#define WAVES_Y 2       /* waves per block (independent y-subtiles) */
#define STRIP_OUT 240   /* output columns per wave; input strip = 256 cols */
#define EPS 0.002f
#define RING 10         /* register ring of raw rows (7 window + 3 prefetch) */

#define NSTRIPS 13
#define NYT 32          /* y-tiles (of WAVES_Y*SUB_H=64 rows) */
#define NCH 3
#define NWG (NSTRIPS * NYT * NCH)   /* 1248 */
#define NXCD 8
#define QXCD (NWG / NXCD)           /* 156, NWG%8==0 -> bijective */

typedef float f32x4 __attribute__((ext_vector_type(4)));

__device__ __forceinline__ float rcp_fast(float x) { return __builtin_amdgcn_rcpf(x); }

// Whole-wave lane shifts at VALU speed (no LDS pipe, no lgkm waits).
// 0x138 = wf_sr1: lane i <- lane i-1 (lane 0 <- 0 via bound_ctrl)  == shfl_up(1)
// 0x130 = wf_sl1: lane i <- lane i+1 (lane 63 <- 0)                == shfl_down(1)
__device__ __forceinline__ float dpp_up1(float x) {
    return __int_as_float(__builtin_amdgcn_update_dpp(0, __float_as_int(x), 0x138, 0xf, 0xf, true));
}
__device__ __forceinline__ float dpp_dn1(float x) {
    return __int_as_float(__builtin_amdgcn_update_dpp(0, __float_as_int(x), 0x130, 0xf, 0xf, true));
}

// 2 independent waves per block, each owning a 32-row x 240-col output tile.
// Raw input rows in a 10-deep register ring (fully unrolled -> compile-time
// indices); add-rows prefetched 3 iterations ahead; horizontal 7-sums via DPP
// wave shifts. No LDS, no barriers. NT stores.
// XCD swizzle: work is assigned column-major so vertically-adjacent tiles
// (which share 6 halo rows) co-reside on one XCD's L2.
__global__ __launch_bounds__(64 * WAVES_Y) void ProgressiveTransfer_kernel(
    const float* __restrict__ G, const float* __restrict__ S,
    float* __restrict__ out, int H, int W)
{
    const int t  = threadIdx.x;                        // lane 0..63
    const int wv = threadIdx.y;

    // ---- bijective XCD swizzle (m204; NWG % 8 == 0 so q-form suffices) ----
    const int orig = blockIdx.x + NSTRIPS * (blockIdx.y + NYT * blockIdx.z);
    const int wg   = (orig % NXCD) * QXCD + orig / NXCD;
    // column-major decode: consecutive wg walk DOWN a strip column
    const int ch  = wg / (NSTRIPS * NYT);
    const int rem = wg - ch * (NSTRIPS * NYT);
    const int sx  = rem / NYT;                         // strip index 0..12
    const int sy  = rem % NYT;                         // y-tile index 0..31

    const int y0 = (sy * WAVES_Y + wv) * SUB_H;
    const int col0 = sx * STRIP_OUT - 8 + 4 * t;
    const bool cin = (col0 >= 0) && (col0 + 3 < W);    // float4 all-in or all-out

    const size_t plane = (size_t)H * W;
    const float* Gp = G + (size_t)ch * plane;
    const float* Sp = S + (size_t)ch * plane;

    auto ld = [&](const float* __restrict__ P, int r) -> f32x4 {
        if (cin && r >= 0 && r < H)
            return *reinterpret_cast<const f32x4*>(P + (size_t)r * W + col0);
        return (f32x4){0.f, 0.f, 0.f, 0.f};
    };

    // Ring slot for image row r is (r - y0 + 3) mod RING.
    f32x4 rg[RING], rs[RING];

    // Vertical window sums over rows [y-3, y+3] for the lane's 4 columns.
    float g1[4] = {0,0,0,0}, g2[4] = {0,0,0,0};
    float s1[4] = {0,0,0,0}, s2[4] = {0,0,0,0};

    // Prologue: rows y0-3..y0+2 -> slots 0..5 (init), y0+3..y0+5 -> slots 6..8
    // (prefetch for iters 0..2). 18 loads issued back-to-back (max MLP).
#pragma unroll
    for (int k = 0; k < 9; ++k) rg[k] = ld(Gp, y0 - HALO + k);
#pragma unroll
    for (int k = 0; k < 9; ++k) rs[k] = ld(Sp, y0 - HALO + k);
#pragma unroll
    for (int k = 0; k < 6; ++k) {
#pragma unroll
        for (int j = 0; j < 4; ++j) {
            g1[j] += rg[k][j]; g2[j] = fmaf(rg[k][j], rg[k][j], g2[j]);
            s1[j] += rs[k][j]; s2[j] = fmaf(rs[k][j], rs[k][j], s2[j]);
        }
    }

    // Per-column horizontal clipped counts (loop-invariant).
    float cntx[4];
#pragma unroll
    for (int j = 0; j < 4; ++j) {
        const int x = col0 + j;
        cntx[j] = (float)(min(x + HALO, W - 1) - max(x - HALO, 0) + 1);
    }

    const bool wout = (t >= 2) && (t < 62) && (col0 < W);

#pragma unroll
    for (int i = 0; i < SUB_H; ++i) {
        const int y = y0 + i;

        // Drop row y-4 from the ring (slot holds zeros when y-4 < 0).
        if (i >= 1) {
            const int sl = (i - 1) % RING;
#pragma unroll
            for (int j = 0; j < 4; ++j) {
                g1[j] -= rg[sl][j]; g2[j] = fmaf(-rg[sl][j], rg[sl][j], g2[j]);
                s1[j] -= rs[sl][j]; s2[j] = fmaf(-rs[sl][j], rs[sl][j], s2[j]);
            }
        }
        // Gain row y+3 (loaded 3 iterations ago).
        {
            const int al = (i + 6) % RING;
#pragma unroll
            for (int j = 0; j < 4; ++j) {
                g1[j] += rg[al][j]; g2[j] = fmaf(rg[al][j], rg[al][j], g2[j]);
                s1[j] += rs[al][j]; s2[j] = fmaf(rs[al][j], rs[al][j], s2[j]);
            }
        }
        // Prefetch add-row of iteration i+3 (row y+6) into its slot.
        // (Slot (i+9)%RING was sub-read above in this same iteration.)
        if (i + 3 < SUB_H) {
            const int pl = (i + 9) % RING;
            rg[pl] = ld(Gp, y + 6);
            rs[pl] = ld(Sp, y + 6);
        }

        // Horizontal 7-sums via DPP wave shifts (pure VALU).
        float hg1[4], hg2[4], hs1[4], hs2[4];
        auto hsum = [&](const float* c, float* o) {
            const float t1 = c[0] + c[1], t2 = c[2] + c[3];
            const float S4 = t1 + t2;
            const float sfx3 = c[1] + t2;     // c1+c2+c3
            const float pfx3 = t1 + c[2];     // c0+c1+c2
            const float S1m = dpp_up1(c[3]);
            const float S2m = dpp_up1(t2);
            const float S3m = dpp_up1(sfx3);
            const float P1p = dpp_dn1(c[0]);
            const float P2p = dpp_dn1(t1);
            const float P3p = dpp_dn1(pfx3);
            o[0] = S3m + S4;
            o[1] = S2m + S4 + P1p;
            o[2] = S1m + S4 + P2p;
            o[3] = S4 + P3p;
        };
        hsum(g1, hg1); hsum(g2, hg2); hsum(s1, hs1); hsum(s2, hs2);

        const float cnty = (float)(min(y + HALO, H - 1) - max(y - HALO, 0) + 1);

        f32x4 av, bv;
#pragma unroll
        for (int j = 0; j < 4; ++j) {
            const float cnt  = cntx[j] * cnty;
            const float inv  = rcp_fast(cnt);
            const float invm = rcp_fast(cnt - 1.0f);
            const float mg = hg1[j] * inv;
            const float ms = hs1[j] * inv;
            const float varg = (hg2[j] - hg1[j] * mg) * invm;
            const float vars = (hs2[j] - hs1[j] * ms) * invm;
            const float stdg = __builtin_amdgcn_sqrtf(fmaxf(varg, 0.0f));
            const float stds = __builtin_amdgcn_sqrtf(fmaxf(vars, 0.0f));
            const float alpha = stdg * rcp_fast(stds + EPS);
            av[j] = alpha;
            bv[j] = mg - alpha * ms;
        }

        if (wout) {
            const size_t base = (size_t)ch * plane + (size_t)y * W + col0;
            __builtin_nontemporal_store(av, reinterpret_cast<f32x4*>(out + base));
            __builtin_nontemporal_store(bv, reinterpret_cast<f32x4*>(out + 3 * plane + base));
        }
    }
}

extern "C" void kernel_launch(void* const* d_in, const int* in_sizes, int n_in,
                              void* d_out, int out_size, void* d_ws, size_t ws_size,
                              hipStream_t stream) {
    (void)n_in; (void)d_ws; (void)ws_size; (void)in_sizes; (void)out_size;
    const float* guidance = (const float*)d_in[0];
    const float* source   = (const float*)d_in[1];
    float* out = (float*)d_out;

    const int H = 2048, W = 3072;

    dim3 block(64, WAVES_Y, 1);
    dim3 grid(NSTRIPS, NYT, NCH);                      // 13 x 32 x 3 = 1248
    ProgressiveTransfer_kernel<<<grid, block, 0, stream>>>(guidance, source, out, H, W);
}